// Round 9
// baseline (312.942 us; speedup 1.0000x reference)
//
#include <hip/hip_runtime.h>
#include <hip/hip_fp16.h>
#include <math.h>

#define NN 100000
#define NE 1600000
#define D  64
#define NBLK 391  // ceil(NN/256)

typedef _Float16 half2v __attribute__((ext_vector_type(2)));

// packed CSR entry: [col:17][ex_fp16_no_sign:15]  (col < 2^17, ex > 0)
__device__ __forceinline__ unsigned int pack_entry(int col, float ex) {
    unsigned short hb = __half_as_ushort(__float2half(ex));
    return ((unsigned int)col << 15) | (unsigned int)(hb & 0x7FFFu);
}
__device__ __forceinline__ float unpack_ex(unsigned int pk) {
    return __half2float(__ushort_as_half((unsigned short)(pk & 0x7FFFu)));
}

// ---------------- K_prep: znh = z/||z|| (fp16), xwh = x @ W^T (fp16); cnt=0 ----------------
__global__ __launch_bounds__(256) void k_prep(const float* __restrict__ z,
                                              const float* __restrict__ x,
                                              const float* __restrict__ W,
                                              __half* __restrict__ znh,
                                              __half* __restrict__ xwh,
                                              int* __restrict__ cnt) {
    __shared__ float Wt[64 * 65];  // Wt[d*65 + j] = W[j*64 + d]
    for (int i = threadIdx.x; i < 4096; i += 256) {
        Wt[(i & 63) * 65 + (i >> 6)] = W[i];
    }
    __syncthreads();
    const int lane = threadIdx.x & 63;
    int wave = blockIdx.x * 4 + (threadIdx.x >> 6);
    int nWaves = gridDim.x * 4;
    for (int n = wave; n < NN; n += nWaves) {
        float zv = z[n * D + lane];
        float s = zv * zv;
#pragma unroll
        for (int off = 32; off; off >>= 1) s += __shfl_xor(s, off);
        float inv = 1.0f / sqrtf(fmaxf(s, 1e-18f));
        znh[n * D + lane] = __float2half(zv * inv);
        float xv = x[n * D + lane];
        float y0 = 0.0f, y1 = 0.0f, y2 = 0.0f, y3 = 0.0f;
#pragma unroll
        for (int d = 0; d < 64; d += 4) {
            y0 = fmaf(__shfl(xv, d), Wt[d * 65 + lane], y0);
            y1 = fmaf(__shfl(xv, d + 1), Wt[(d + 1) * 65 + lane], y1);
            y2 = fmaf(__shfl(xv, d + 2), Wt[(d + 2) * 65 + lane], y2);
            y3 = fmaf(__shfl(xv, d + 3), Wt[(d + 3) * 65 + lane], y3);
        }
        xwh[n * D + lane] = __float2half((y0 + y1) + (y2 + y3));
        if (lane == 0) cnt[n] = 0;
    }
}

// ---------------- K_count: edges per destination row; atomic old value = stable rank ----------------
__global__ __launch_bounds__(256) void k_count(const int* __restrict__ ei,
                                               int* __restrict__ cnt,
                                               int* __restrict__ rank) {
    int i = blockIdx.x * blockDim.x + threadIdx.x;
    int stride = gridDim.x * blockDim.x;
    for (int e = i; e < NE; e += stride) {
        int r = __builtin_nontemporal_load(&ei[e]);
        rank[e] = atomicAdd(&cnt[r], 1);
    }
}

// ---------------- scan: exclusive prefix sum of cnt -> row_start ----------------
__global__ __launch_bounds__(256) void k_scan1(const int* __restrict__ cnt,
                                               int* __restrict__ inc,
                                               int* __restrict__ bsum) {
    __shared__ int sh[256];
    int gid = blockIdx.x * 256 + threadIdx.x;
    int v = (gid < NN) ? cnt[gid] : 0;
    sh[threadIdx.x] = v;
    __syncthreads();
    for (int off = 1; off < 256; off <<= 1) {
        int t = (threadIdx.x >= off) ? sh[threadIdx.x - off] : 0;
        __syncthreads();
        sh[threadIdx.x] += t;
        __syncthreads();
    }
    if (gid < NN) inc[gid] = sh[threadIdx.x];
    if (threadIdx.x == 255) bsum[blockIdx.x] = sh[255];
}

__global__ __launch_bounds__(512) void k_scan2(int* __restrict__ bsum) {
    __shared__ int sh[512];
    int v = (threadIdx.x < NBLK) ? bsum[threadIdx.x] : 0;
    sh[threadIdx.x] = v;
    __syncthreads();
    for (int off = 1; off < 512; off <<= 1) {
        int t = (threadIdx.x >= off) ? sh[threadIdx.x - off] : 0;
        __syncthreads();
        sh[threadIdx.x] += t;
        __syncthreads();
    }
    if (threadIdx.x < NBLK) bsum[threadIdx.x] = sh[threadIdx.x] - v;  // exclusive
}

__global__ __launch_bounds__(256) void k_scan3(const int* __restrict__ cnt,
                                               const int* __restrict__ inc,
                                               const int* __restrict__ bsum,
                                               int* __restrict__ row_start) {
    int gid = blockIdx.x * 256 + threadIdx.x;
    if (gid < NN) {
        row_start[gid] = inc[gid] - cnt[gid] + bsum[blockIdx.x];
    }
}

// ---------------- K_edge_place: in-lane dot + exp + atomic-free nt scatter ----------------
__global__ __launch_bounds__(256) void k_edge_place(const __half* __restrict__ znh,
                                                    const int* __restrict__ ei,
                                                    const int* __restrict__ rank,
                                                    const int* __restrict__ row_start,
                                                    const float* __restrict__ alpha_p,
                                                    const float* __restrict__ bias_p,
                                                    unsigned int* __restrict__ packed) {
    int e = blockIdx.x * 256 + threadIdx.x;
    if (e >= NE) return;
    const float alpha = *alpha_p;
    const float bias = *bias_p;
    const float Mest = fabsf(alpha) + bias;  // >= max logit since |corr| <= 1
    int r = __builtin_nontemporal_load(&ei[e]);
    int c = __builtin_nontemporal_load(&ei[NE + e]);
    int rk = __builtin_nontemporal_load(&rank[e]);
    const float4* zi4 = (const float4*)(znh + (size_t)r * D);
    const float4* zj4 = (const float4*)(znh + (size_t)c * D);
    float4 a[8], bb[8];
#pragma unroll
    for (int k = 0; k < 8; ++k) { a[k] = zi4[k]; bb[k] = zj4[k]; }
    float dot = 0.0f;
#pragma unroll
    for (int k = 0; k < 8; ++k) {
        const half2v* ha = (const half2v*)&a[k];
        const half2v* hb = (const half2v*)&bb[k];
#pragma unroll
        for (int q = 0; q < 4; ++q) {
#if defined(__has_builtin) && __has_builtin(__builtin_amdgcn_fdot2)
            dot = __builtin_amdgcn_fdot2(ha[q], hb[q], dot, false);
#else
            float2 fa = __half22float2(*(const __half2*)&ha[q]);
            float2 fb = __half22float2(*(const __half2*)&hb[q]);
            dot = fmaf(fa.x, fb.x, dot);
            dot = fmaf(fa.y, fb.y, dot);
#endif
        }
    }
    float ex = __expf(alpha * dot + bias - Mest);
    int pos = row_start[r] + rk;
    __builtin_nontemporal_store(pack_entry(c, ex), &packed[pos]);
}

// ---------------- K_gather: one wave per node, scalar-addressed y-row gather, no LDS ----------------
__global__ __launch_bounds__(256) void k_gather(const __half* __restrict__ xwh,
                                                const unsigned int* __restrict__ packed,
                                                const int* __restrict__ row_start,
                                                const int* __restrict__ cnt,
                                                const float* __restrict__ b,
                                                float* __restrict__ out) {
    const int lane = threadIdx.x & 63;
    int n = (blockIdx.x * blockDim.x + threadIdx.x) >> 6;  // one wave per node
    if (n >= NN) return;
    int rs = row_start[n];
    int c = cnt[n];
    float bv = b[lane];
    float acc = 0.0f;
    float dsum = 0.0f;
    for (int base = 0; base < c; base += 64) {
        int m = min(64, c - base);
        int idx = base + lane;
        unsigned int pk = (idx < c) ? packed[rs + idx] : 0u;
        // chunk-wide denom sum (one butterfly per 64 edges)
        float t = (idx < c) ? unpack_ex(pk) : 0.0f;
#pragma unroll
        for (int off = 32; off; off >>= 1) t += __shfl_xor(t, off);
        dsum += t;
        int j = 0;
        for (; j + 8 <= m; j += 8) {
            unsigned int p0 = (unsigned int)__builtin_amdgcn_readlane((int)pk, j);
            unsigned int p1 = (unsigned int)__builtin_amdgcn_readlane((int)pk, j + 1);
            unsigned int p2 = (unsigned int)__builtin_amdgcn_readlane((int)pk, j + 2);
            unsigned int p3 = (unsigned int)__builtin_amdgcn_readlane((int)pk, j + 3);
            unsigned int p4 = (unsigned int)__builtin_amdgcn_readlane((int)pk, j + 4);
            unsigned int p5 = (unsigned int)__builtin_amdgcn_readlane((int)pk, j + 5);
            unsigned int p6 = (unsigned int)__builtin_amdgcn_readlane((int)pk, j + 6);
            unsigned int p7 = (unsigned int)__builtin_amdgcn_readlane((int)pk, j + 7);
            float x0 = __half2float(xwh[(size_t)(p0 >> 15) * D + lane]);
            float x1 = __half2float(xwh[(size_t)(p1 >> 15) * D + lane]);
            float x2 = __half2float(xwh[(size_t)(p2 >> 15) * D + lane]);
            float x3 = __half2float(xwh[(size_t)(p3 >> 15) * D + lane]);
            float x4 = __half2float(xwh[(size_t)(p4 >> 15) * D + lane]);
            float x5 = __half2float(xwh[(size_t)(p5 >> 15) * D + lane]);
            float x6 = __half2float(xwh[(size_t)(p6 >> 15) * D + lane]);
            float x7 = __half2float(xwh[(size_t)(p7 >> 15) * D + lane]);
            acc = fmaf(unpack_ex(p0), x0, acc);
            acc = fmaf(unpack_ex(p1), x1, acc);
            acc = fmaf(unpack_ex(p2), x2, acc);
            acc = fmaf(unpack_ex(p3), x3, acc);
            acc = fmaf(unpack_ex(p4), x4, acc);
            acc = fmaf(unpack_ex(p5), x5, acc);
            acc = fmaf(unpack_ex(p6), x6, acc);
            acc = fmaf(unpack_ex(p7), x7, acc);
        }
        for (; j < m; ++j) {
            unsigned int p0 = (unsigned int)__builtin_amdgcn_readlane((int)pk, j);
            float x0 = __half2float(xwh[(size_t)(p0 >> 15) * D + lane]);
            acc = fmaf(unpack_ex(p0), x0, acc);
        }
    }
    out[n * D + lane] = acc / (dsum + 1e-9f) + bv;
}

extern "C" void kernel_launch(void* const* d_in, const int* in_sizes, int n_in,
                              void* d_out, int out_size, void* d_ws, size_t ws_size,
                              hipStream_t stream) {
    const float* x = (const float*)d_in[0];
    const int* ei = (const int*)d_in[1];  // [2, NE] int32
    const float* z = (const float*)d_in[2];
    const float* W = (const float*)d_in[3];
    const float* b = (const float*)d_in[4];
    const float* alpha = (const float*)d_in[5];
    const float* bias_edge = (const float*)d_in[6];
    float* out = (float*)d_out;  // [NN, D]

    // workspace layout
    char* ws = (char*)d_ws;
    size_t off = 0;
    __half* znh = (__half*)(ws + off); off += (size_t)NN * D * 2;       // 12.8 MB
    __half* xwh = (__half*)(ws + off); off += (size_t)NN * D * 2;       // 12.8 MB
    unsigned int* packed = (unsigned int*)(ws + off); off += (size_t)NE * 4;  // 6.4 MB
    int* rank = (int*)(ws + off); off += (size_t)NE * 4;                // 6.4 MB
    int* cnt = (int*)(ws + off); off += (size_t)NN * 4;
    int* inc = (int*)(ws + off); off += (size_t)NN * 4;
    int* row_start = (int*)(ws + off); off += (size_t)NN * 4;
    int* bsum = (int*)(ws + off); off += 512 * 4;

    k_prep<<<2048, 256, 0, stream>>>(z, x, W, znh, xwh, cnt);
    k_count<<<2048, 256, 0, stream>>>(ei, cnt, rank);
    k_scan1<<<NBLK, 256, 0, stream>>>(cnt, inc, bsum);
    k_scan2<<<1, 512, 0, stream>>>(bsum);
    k_scan3<<<NBLK, 256, 0, stream>>>(cnt, inc, bsum, row_start);
    k_edge_place<<<(NE + 255) / 256, 256, 0, stream>>>(znh, ei, rank, row_start, alpha, bias_edge, packed);
    k_gather<<<(NN * 64 + 255) / 256, 256, 0, stream>>>(xwh, packed, row_start, cnt, b, out);
}

// Round 10
// 305.347 us; speedup vs baseline: 1.0249x; 1.0249x over previous
//
#include <hip/hip_runtime.h>
#include <hip/hip_fp16.h>
#include <math.h>

#define NN 100000
#define NE 1600000
#define D  64
#define NBLK 391  // ceil(NN/256)

typedef _Float16 half2v __attribute__((ext_vector_type(2)));

// packed entry (in-register only): [col:17][ex_fp16_no_sign:15]  (col < 2^17, ex >= 0)
__device__ __forceinline__ unsigned int pack_entry(int col, float ex) {
    unsigned short hb = __half_as_ushort(__float2half(ex));
    return ((unsigned int)col << 15) | (unsigned int)(hb & 0x7FFFu);
}
__device__ __forceinline__ float unpack_ex(unsigned int pk) {
    return __half2float(__ushort_as_half((unsigned short)(pk & 0x7FFFu)));
}

// ---------------- K_prep: znh = z/||z|| (fp16), xwh = x @ W^T (fp16); cnt=0 ----------------
__global__ __launch_bounds__(256) void k_prep(const float* __restrict__ z,
                                              const float* __restrict__ x,
                                              const float* __restrict__ W,
                                              __half* __restrict__ znh,
                                              __half* __restrict__ xwh,
                                              int* __restrict__ cnt) {
    __shared__ float Wt[64 * 65];  // Wt[d*65 + j] = W[j*64 + d]
    for (int i = threadIdx.x; i < 4096; i += 256) {
        Wt[(i & 63) * 65 + (i >> 6)] = W[i];
    }
    __syncthreads();
    const int lane = threadIdx.x & 63;
    int wave = blockIdx.x * 4 + (threadIdx.x >> 6);
    int nWaves = gridDim.x * 4;
    for (int n = wave; n < NN; n += nWaves) {
        float zv = z[n * D + lane];
        float s = zv * zv;
#pragma unroll
        for (int off = 32; off; off >>= 1) s += __shfl_xor(s, off);
        float inv = 1.0f / sqrtf(fmaxf(s, 1e-18f));
        znh[n * D + lane] = __float2half(zv * inv);
        float xv = x[n * D + lane];
        float y0 = 0.0f, y1 = 0.0f, y2 = 0.0f, y3 = 0.0f;
#pragma unroll
        for (int d = 0; d < 64; d += 4) {
            y0 = fmaf(__shfl(xv, d), Wt[d * 65 + lane], y0);
            y1 = fmaf(__shfl(xv, d + 1), Wt[(d + 1) * 65 + lane], y1);
            y2 = fmaf(__shfl(xv, d + 2), Wt[(d + 2) * 65 + lane], y2);
            y3 = fmaf(__shfl(xv, d + 3), Wt[(d + 3) * 65 + lane], y3);
        }
        xwh[n * D + lane] = __float2half((y0 + y1) + (y2 + y3));
        if (lane == 0) cnt[n] = 0;
    }
}

// ---------------- K_count: edges per destination row; atomic old value = stable rank ----------------
__global__ __launch_bounds__(256) void k_count(const int* __restrict__ ei,
                                               int* __restrict__ cnt,
                                               int* __restrict__ rank) {
    int i = blockIdx.x * blockDim.x + threadIdx.x;
    int stride = gridDim.x * blockDim.x;
    for (int e = i; e < NE; e += stride) {
        int r = __builtin_nontemporal_load(&ei[e]);
        rank[e] = atomicAdd(&cnt[r], 1);
    }
}

// ---------------- scan: exclusive prefix sum of cnt -> row_start ----------------
__global__ __launch_bounds__(256) void k_scan1(const int* __restrict__ cnt,
                                               int* __restrict__ inc,
                                               int* __restrict__ bsum) {
    __shared__ int sh[256];
    int gid = blockIdx.x * 256 + threadIdx.x;
    int v = (gid < NN) ? cnt[gid] : 0;
    sh[threadIdx.x] = v;
    __syncthreads();
    for (int off = 1; off < 256; off <<= 1) {
        int t = (threadIdx.x >= off) ? sh[threadIdx.x - off] : 0;
        __syncthreads();
        sh[threadIdx.x] += t;
        __syncthreads();
    }
    if (gid < NN) inc[gid] = sh[threadIdx.x];
    if (threadIdx.x == 255) bsum[blockIdx.x] = sh[255];
}

__global__ __launch_bounds__(512) void k_scan2(int* __restrict__ bsum) {
    __shared__ int sh[512];
    int v = (threadIdx.x < NBLK) ? bsum[threadIdx.x] : 0;
    sh[threadIdx.x] = v;
    __syncthreads();
    for (int off = 1; off < 512; off <<= 1) {
        int t = (threadIdx.x >= off) ? sh[threadIdx.x - off] : 0;
        __syncthreads();
        sh[threadIdx.x] += t;
        __syncthreads();
    }
    if (threadIdx.x < NBLK) bsum[threadIdx.x] = sh[threadIdx.x] - v;  // exclusive
}

__global__ __launch_bounds__(256) void k_scan3(const int* __restrict__ cnt,
                                               const int* __restrict__ inc,
                                               const int* __restrict__ bsum,
                                               int* __restrict__ row_start) {
    int gid = blockIdx.x * 256 + threadIdx.x;
    if (gid < NN) {
        row_start[gid] = inc[gid] - cnt[gid] + bsum[blockIdx.x];
    }
}

// ---------------- K_place: atomic-free colidx scatter ----------------
__global__ __launch_bounds__(256) void k_place(const int* __restrict__ ei,
                                               const int* __restrict__ rank,
                                               const int* __restrict__ row_start,
                                               int* __restrict__ colidx) {
    int e = blockIdx.x * 256 + threadIdx.x;
    if (e >= NE) return;
    int r = __builtin_nontemporal_load(&ei[e]);
    int c = __builtin_nontemporal_load(&ei[NE + e]);
    int rk = __builtin_nontemporal_load(&rank[e]);
    __builtin_nontemporal_store(c, &colidx[row_start[r] + rk]);
}

// ---------------- K_node: fused per-node dot+exp+softmax+gather (+bias) ----------------
__global__ __launch_bounds__(256) void k_node(const __half* __restrict__ znh,
                                              const __half* __restrict__ xwh,
                                              const int* __restrict__ colidx,
                                              const int* __restrict__ row_start,
                                              const int* __restrict__ cnt,
                                              const float* __restrict__ b,
                                              const float* __restrict__ alpha_p,
                                              const float* __restrict__ bias_p,
                                              float* __restrict__ out) {
    const int lane = threadIdx.x & 63;
    int n = (blockIdx.x * blockDim.x + threadIdx.x) >> 6;  // one wave per node
    if (n >= NN) return;
    const float alpha = *alpha_p;
    const float bias = *bias_p;
    const float Mest = fabsf(alpha) + bias;  // >= max logit since |corr| <= 1
    int rs = row_start[n];
    int c = cnt[n];
    float bv = b[lane];
    // zi: this node's normalized z row (all lanes same addresses -> broadcast lines)
    const float4* zi4 = (const float4*)(znh + (size_t)n * D);
    float4 zi[8];
#pragma unroll
    for (int k = 0; k < 8; ++k) zi[k] = zi4[k];
    float acc = 0.0f;
    float dsum = 0.0f;
    for (int base = 0; base < c; base += 64) {
        int m = min(64, c - base);
        int idx = base + lane;
        int col = (idx < c) ? colidx[rs + idx] : 0;
        // ---- phase A: in-lane dot(zn[n], zn[col]) ----
        const float4* zj4 = (const float4*)(znh + (size_t)col * D);
        float4 zj[8];
#pragma unroll
        for (int k = 0; k < 8; ++k) zj[k] = zj4[k];
        float dot = 0.0f;
#pragma unroll
        for (int k = 0; k < 8; ++k) {
            const half2v* ha = (const half2v*)&zi[k];
            const half2v* hb = (const half2v*)&zj[k];
#pragma unroll
            for (int q = 0; q < 4; ++q) {
#if defined(__has_builtin) && __has_builtin(__builtin_amdgcn_fdot2)
                dot = __builtin_amdgcn_fdot2(ha[q], hb[q], dot, false);
#else
                float2 fa = __half22float2(*(const __half2*)&ha[q]);
                float2 fb = __half22float2(*(const __half2*)&hb[q]);
                dot = fmaf(fa.x, fb.x, dot);
                dot = fmaf(fa.y, fb.y, dot);
#endif
            }
        }
        float ex = (idx < c) ? __expf(alpha * dot + bias - Mest) : 0.0f;
        unsigned int pk = pack_entry(col, ex);
        // chunk-wide denom sum (one butterfly per 64 edges)
        float t = ex;
#pragma unroll
        for (int off = 32; off; off >>= 1) t += __shfl_xor(t, off);
        dsum += t;
        // ---- phase B: broadcast + coalesced xwh gather ----
        int j = 0;
        for (; j + 8 <= m; j += 8) {
            unsigned int p0 = (unsigned int)__builtin_amdgcn_readlane((int)pk, j);
            unsigned int p1 = (unsigned int)__builtin_amdgcn_readlane((int)pk, j + 1);
            unsigned int p2 = (unsigned int)__builtin_amdgcn_readlane((int)pk, j + 2);
            unsigned int p3 = (unsigned int)__builtin_amdgcn_readlane((int)pk, j + 3);
            unsigned int p4 = (unsigned int)__builtin_amdgcn_readlane((int)pk, j + 4);
            unsigned int p5 = (unsigned int)__builtin_amdgcn_readlane((int)pk, j + 5);
            unsigned int p6 = (unsigned int)__builtin_amdgcn_readlane((int)pk, j + 6);
            unsigned int p7 = (unsigned int)__builtin_amdgcn_readlane((int)pk, j + 7);
            float x0 = __half2float(xwh[(size_t)(p0 >> 15) * D + lane]);
            float x1 = __half2float(xwh[(size_t)(p1 >> 15) * D + lane]);
            float x2 = __half2float(xwh[(size_t)(p2 >> 15) * D + lane]);
            float x3 = __half2float(xwh[(size_t)(p3 >> 15) * D + lane]);
            float x4 = __half2float(xwh[(size_t)(p4 >> 15) * D + lane]);
            float x5 = __half2float(xwh[(size_t)(p5 >> 15) * D + lane]);
            float x6 = __half2float(xwh[(size_t)(p6 >> 15) * D + lane]);
            float x7 = __half2float(xwh[(size_t)(p7 >> 15) * D + lane]);
            acc = fmaf(unpack_ex(p0), x0, acc);
            acc = fmaf(unpack_ex(p1), x1, acc);
            acc = fmaf(unpack_ex(p2), x2, acc);
            acc = fmaf(unpack_ex(p3), x3, acc);
            acc = fmaf(unpack_ex(p4), x4, acc);
            acc = fmaf(unpack_ex(p5), x5, acc);
            acc = fmaf(unpack_ex(p6), x6, acc);
            acc = fmaf(unpack_ex(p7), x7, acc);
        }
        for (; j < m; ++j) {
            unsigned int p0 = (unsigned int)__builtin_amdgcn_readlane((int)pk, j);
            float x0 = __half2float(xwh[(size_t)(p0 >> 15) * D + lane]);
            acc = fmaf(unpack_ex(p0), x0, acc);
        }
    }
    out[n * D + lane] = acc / (dsum + 1e-9f) + bv;
}

extern "C" void kernel_launch(void* const* d_in, const int* in_sizes, int n_in,
                              void* d_out, int out_size, void* d_ws, size_t ws_size,
                              hipStream_t stream) {
    const float* x = (const float*)d_in[0];
    const int* ei = (const int*)d_in[1];  // [2, NE] int32
    const float* z = (const float*)d_in[2];
    const float* W = (const float*)d_in[3];
    const float* b = (const float*)d_in[4];
    const float* alpha = (const float*)d_in[5];
    const float* bias_edge = (const float*)d_in[6];
    float* out = (float*)d_out;  // [NN, D]

    // workspace layout
    char* ws = (char*)d_ws;
    size_t off = 0;
    __half* znh = (__half*)(ws + off); off += (size_t)NN * D * 2;       // 12.8 MB
    __half* xwh = (__half*)(ws + off); off += (size_t)NN * D * 2;       // 12.8 MB
    int* colidx = (int*)(ws + off); off += (size_t)NE * 4;              // 6.4 MB
    int* rank = (int*)(ws + off); off += (size_t)NE * 4;                // 6.4 MB
    int* cnt = (int*)(ws + off); off += (size_t)NN * 4;
    int* inc = (int*)(ws + off); off += (size_t)NN * 4;
    int* row_start = (int*)(ws + off); off += (size_t)NN * 4;
    int* bsum = (int*)(ws + off); off += 512 * 4;

    k_prep<<<2048, 256, 0, stream>>>(z, x, W, znh, xwh, cnt);
    k_count<<<2048, 256, 0, stream>>>(ei, cnt, rank);
    k_scan1<<<NBLK, 256, 0, stream>>>(cnt, inc, bsum);
    k_scan2<<<1, 512, 0, stream>>>(bsum);
    k_scan3<<<NBLK, 256, 0, stream>>>(cnt, inc, bsum, row_start);
    k_place<<<(NE + 255) / 256, 256, 0, stream>>>(ei, rank, row_start, colidx);
    k_node<<<(NN * 64 + 255) / 256, 256, 0, stream>>>(znh, xwh, colidx, row_start, cnt, b, alpha, bias_edge, out);
}

// Round 11
// 260.771 us; speedup vs baseline: 1.2001x; 1.1709x over previous
//
#include <hip/hip_runtime.h>
#include <hip/hip_fp16.h>
#include <math.h>

#define NN 100000
#define NE 1600000
#define D  64
#define NBLK 391  // ceil(NN/256)

typedef _Float16 half2v __attribute__((ext_vector_type(2)));

// in-register packed entry: [col:17][ex_fp16_no_sign:15]  (col < 2^17, ex in (0,1])
__device__ __forceinline__ unsigned int pack_entry(int col, float ex) {
    unsigned short hb = __half_as_ushort(__float2half(ex));
    return ((unsigned int)col << 15) | (unsigned int)(hb & 0x7FFFu);
}
__device__ __forceinline__ float unpack_ex(unsigned int pk) {
    return __half2float(__ushort_as_half((unsigned short)(pk & 0x7FFFu)));
}

// ---------------- K_prep_count: zx[n][0:64]=z/||z||, zx[n][64:128]=x@W^T (fp16);
//                  then edge count with rank+row packed (cnt pre-zeroed by memset) ----------------
__global__ __launch_bounds__(256) void k_prep_count(const float* __restrict__ z,
                                                    const float* __restrict__ x,
                                                    const float* __restrict__ W,
                                                    __half* __restrict__ zx,
                                                    const int* __restrict__ ei,
                                                    int* __restrict__ cnt,
                                                    unsigned int* __restrict__ rankr) {
    __shared__ float Wt[64 * 65];  // Wt[d*65 + j] = W[j*64 + d]
    for (int i = threadIdx.x; i < 4096; i += 256) {
        Wt[(i & 63) * 65 + (i >> 6)] = W[i];
    }
    __syncthreads();
    const int lane = threadIdx.x & 63;
    int wave = blockIdx.x * 4 + (threadIdx.x >> 6);
    int nWaves = gridDim.x * 4;
    for (int n = wave; n < NN; n += nWaves) {
        float zv = z[n * D + lane];
        float s = zv * zv;
#pragma unroll
        for (int off = 32; off; off >>= 1) s += __shfl_xor(s, off);
        float inv = 1.0f / sqrtf(fmaxf(s, 1e-18f));
        zx[(size_t)n * 128 + lane] = __float2half(zv * inv);
        float xv = x[n * D + lane];
        float y0 = 0.0f, y1 = 0.0f, y2 = 0.0f, y3 = 0.0f;
#pragma unroll
        for (int d = 0; d < 64; d += 4) {
            y0 = fmaf(__shfl(xv, d), Wt[d * 65 + lane], y0);
            y1 = fmaf(__shfl(xv, d + 1), Wt[(d + 1) * 65 + lane], y1);
            y2 = fmaf(__shfl(xv, d + 2), Wt[(d + 2) * 65 + lane], y2);
            y3 = fmaf(__shfl(xv, d + 3), Wt[(d + 3) * 65 + lane], y3);
        }
        zx[(size_t)n * 128 + 64 + lane] = __float2half((y0 + y1) + (y2 + y3));
    }
    // ---- independent count phase (cnt zeroed before this kernel) ----
    int i = blockIdx.x * 256 + threadIdx.x;
    int stride = gridDim.x * 256;
    for (int e = i; e < NE; e += stride) {
        int r = __builtin_nontemporal_load(&ei[e]);
        int rk = atomicAdd(&cnt[r], 1);
        // [r:17][rank:15] — rank < 32768 (in-degree ~Poisson(16))
        __builtin_nontemporal_store(((unsigned int)r << 15) | (unsigned int)rk, &rankr[e]);
    }
}

// ---------------- scan: exclusive prefix sum of cnt -> row_start ----------------
__global__ __launch_bounds__(256) void k_scan1(const int* __restrict__ cnt,
                                               int* __restrict__ inc,
                                               int* __restrict__ bsum) {
    __shared__ int sh[256];
    int gid = blockIdx.x * 256 + threadIdx.x;
    int v = (gid < NN) ? cnt[gid] : 0;
    sh[threadIdx.x] = v;
    __syncthreads();
    for (int off = 1; off < 256; off <<= 1) {
        int t = (threadIdx.x >= off) ? sh[threadIdx.x - off] : 0;
        __syncthreads();
        sh[threadIdx.x] += t;
        __syncthreads();
    }
    if (gid < NN) inc[gid] = sh[threadIdx.x];
    if (threadIdx.x == 255) bsum[blockIdx.x] = sh[255];
}

__global__ __launch_bounds__(512) void k_scan2(int* __restrict__ bsum) {
    __shared__ int sh[512];
    int v = (threadIdx.x < NBLK) ? bsum[threadIdx.x] : 0;
    sh[threadIdx.x] = v;
    __syncthreads();
    for (int off = 1; off < 512; off <<= 1) {
        int t = (threadIdx.x >= off) ? sh[threadIdx.x - off] : 0;
        __syncthreads();
        sh[threadIdx.x] += t;
        __syncthreads();
    }
    if (threadIdx.x < NBLK) bsum[threadIdx.x] = sh[threadIdx.x] - v;  // exclusive
}

__global__ __launch_bounds__(256) void k_scan3(const int* __restrict__ cnt,
                                               const int* __restrict__ inc,
                                               const int* __restrict__ bsum,
                                               int* __restrict__ row_start) {
    int gid = blockIdx.x * 256 + threadIdx.x;
    if (gid < NN) {
        row_start[gid] = inc[gid] - cnt[gid] + bsum[blockIdx.x];
    }
}

// ---------------- K_place: atomic-free colidx scatter (r from rankr; no ei[e] re-read) ----------------
__global__ __launch_bounds__(256) void k_place(const int* __restrict__ ei,
                                               const unsigned int* __restrict__ rankr,
                                               const int* __restrict__ row_start,
                                               int* __restrict__ colidx) {
    int e = blockIdx.x * 256 + threadIdx.x;
    if (e >= NE) return;
    unsigned int rr = __builtin_nontemporal_load(&rankr[e]);
    int c = __builtin_nontemporal_load(&ei[NE + e]);
    int r = (int)(rr >> 15);
    int rk = (int)(rr & 0x7FFFu);
    __builtin_nontemporal_store(c, &colidx[row_start[r] + rk]);
}

// ---------------- K_node: fused per-node dot+exp+softmax+gather (+bias) ----------------
__global__ __launch_bounds__(256) void k_node(const __half* __restrict__ zx,
                                              const int* __restrict__ colidx,
                                              const int* __restrict__ row_start,
                                              const int* __restrict__ cnt,
                                              const float* __restrict__ b,
                                              const float* __restrict__ alpha_p,
                                              const float* __restrict__ bias_p,
                                              float* __restrict__ out) {
    const int lane = threadIdx.x & 63;
    int n = (blockIdx.x * blockDim.x + threadIdx.x) >> 6;  // one wave per node
    if (n >= NN) return;
    const float alpha = *alpha_p;
    const float bias = *bias_p;
    const float Mest = fabsf(alpha) + bias;  // >= max logit since |corr| <= 1
    int rs = row_start[n];
    int c = cnt[n];
    float bv = b[lane];
    // zi: this node's normalized z row (wave-uniform addresses -> broadcast lines)
    const float4* zi4 = (const float4*)(zx + (size_t)n * 128);
    float4 zi[8];
#pragma unroll
    for (int k = 0; k < 8; ++k) zi[k] = zi4[k];
    float acc = 0.0f;
    float dsum = 0.0f;
    for (int base = 0; base < c; base += 64) {
        int m = min(64, c - base);
        int idx = base + lane;
        int col = (idx < c) ? colidx[rs + idx] : 0;
        // ---- phase A: in-lane dot(zn[n], zn[col]) ----
        const float4* zj4 = (const float4*)(zx + (size_t)col * 128);
        float4 zj[8];
#pragma unroll
        for (int k = 0; k < 8; ++k) zj[k] = zj4[k];
        float dot = 0.0f;
#pragma unroll
        for (int k = 0; k < 8; ++k) {
            const half2v* ha = (const half2v*)&zi[k];
            const half2v* hb = (const half2v*)&zj[k];
#pragma unroll
            for (int q = 0; q < 4; ++q) {
#if defined(__has_builtin) && __has_builtin(__builtin_amdgcn_fdot2)
                dot = __builtin_amdgcn_fdot2(ha[q], hb[q], dot, false);
#else
                float2 fa = __half22float2(*(const __half2*)&ha[q]);
                float2 fb = __half22float2(*(const __half2*)&hb[q]);
                dot = fmaf(fa.x, fb.x, dot);
                dot = fmaf(fa.y, fb.y, dot);
#endif
            }
        }
        float ex = (idx < c) ? __expf(alpha * dot + bias - Mest) : 0.0f;
        unsigned int pk = pack_entry(col, ex);
        // chunk-wide denom sum (one butterfly per 64 edges)
        float t = ex;
#pragma unroll
        for (int off = 32; off; off >>= 1) t += __shfl_xor(t, off);
        dsum += t;
        // ---- phase B: broadcast + coalesced xw gather (second half of zx row) ----
        int j = 0;
        for (; j + 8 <= m; j += 8) {
            unsigned int p0 = (unsigned int)__builtin_amdgcn_readlane((int)pk, j);
            unsigned int p1 = (unsigned int)__builtin_amdgcn_readlane((int)pk, j + 1);
            unsigned int p2 = (unsigned int)__builtin_amdgcn_readlane((int)pk, j + 2);
            unsigned int p3 = (unsigned int)__builtin_amdgcn_readlane((int)pk, j + 3);
            unsigned int p4 = (unsigned int)__builtin_amdgcn_readlane((int)pk, j + 4);
            unsigned int p5 = (unsigned int)__builtin_amdgcn_readlane((int)pk, j + 5);
            unsigned int p6 = (unsigned int)__builtin_amdgcn_readlane((int)pk, j + 6);
            unsigned int p7 = (unsigned int)__builtin_amdgcn_readlane((int)pk, j + 7);
            float x0 = __half2float(zx[(size_t)(p0 >> 15) * 128 + 64 + lane]);
            float x1 = __half2float(zx[(size_t)(p1 >> 15) * 128 + 64 + lane]);
            float x2 = __half2float(zx[(size_t)(p2 >> 15) * 128 + 64 + lane]);
            float x3 = __half2float(zx[(size_t)(p3 >> 15) * 128 + 64 + lane]);
            float x4 = __half2float(zx[(size_t)(p4 >> 15) * 128 + 64 + lane]);
            float x5 = __half2float(zx[(size_t)(p5 >> 15) * 128 + 64 + lane]);
            float x6 = __half2float(zx[(size_t)(p6 >> 15) * 128 + 64 + lane]);
            float x7 = __half2float(zx[(size_t)(p7 >> 15) * 128 + 64 + lane]);
            acc = fmaf(unpack_ex(p0), x0, acc);
            acc = fmaf(unpack_ex(p1), x1, acc);
            acc = fmaf(unpack_ex(p2), x2, acc);
            acc = fmaf(unpack_ex(p3), x3, acc);
            acc = fmaf(unpack_ex(p4), x4, acc);
            acc = fmaf(unpack_ex(p5), x5, acc);
            acc = fmaf(unpack_ex(p6), x6, acc);
            acc = fmaf(unpack_ex(p7), x7, acc);
        }
        for (; j < m; ++j) {
            unsigned int p0 = (unsigned int)__builtin_amdgcn_readlane((int)pk, j);
            float x0 = __half2float(zx[(size_t)(p0 >> 15) * 128 + 64 + lane]);
            acc = fmaf(unpack_ex(p0), x0, acc);
        }
    }
    out[n * D + lane] = acc / (dsum + 1e-9f) + bv;
}

extern "C" void kernel_launch(void* const* d_in, const int* in_sizes, int n_in,
                              void* d_out, int out_size, void* d_ws, size_t ws_size,
                              hipStream_t stream) {
    const float* x = (const float*)d_in[0];
    const int* ei = (const int*)d_in[1];  // [2, NE] int32
    const float* z = (const float*)d_in[2];
    const float* W = (const float*)d_in[3];
    const float* b = (const float*)d_in[4];
    const float* alpha = (const float*)d_in[5];
    const float* bias_edge = (const float*)d_in[6];
    float* out = (float*)d_out;  // [NN, D]

    // workspace layout
    char* ws = (char*)d_ws;
    size_t off = 0;
    __half* zx = (__half*)(ws + off); off += (size_t)NN * 128 * 2;          // 25.6 MB
    int* colidx = (int*)(ws + off); off += (size_t)NE * 4;                  // 6.4 MB
    unsigned int* rankr = (unsigned int*)(ws + off); off += (size_t)NE * 4; // 6.4 MB
    int* cnt = (int*)(ws + off); off += (size_t)NN * 4;
    int* inc = (int*)(ws + off); off += (size_t)NN * 4;
    int* row_start = (int*)(ws + off); off += (size_t)NN * 4;
    int* bsum = (int*)(ws + off); off += 512 * 4;

    hipMemsetAsync(cnt, 0, (size_t)NN * 4, stream);
    k_prep_count<<<4096, 256, 0, stream>>>(z, x, W, zx, ei, cnt, rankr);
    k_scan1<<<NBLK, 256, 0, stream>>>(cnt, inc, bsum);
    k_scan2<<<1, 512, 0, stream>>>(bsum);
    k_scan3<<<NBLK, 256, 0, stream>>>(cnt, inc, bsum, row_start);
    k_place<<<(NE + 255) / 256, 256, 0, stream>>>(ei, rankr, row_start, colidx);
    k_node<<<(NN * 64 + 255) / 256, 256, 0, stream>>>(zx, colidx, row_start, cnt, b, alpha, bias_edge, out);
}

// Round 12
// 244.429 us; speedup vs baseline: 1.2803x; 1.0669x over previous
//
#include <hip/hip_runtime.h>
#include <hip/hip_fp16.h>
#include <math.h>

#define NN 100000
#define NE 1600000
#define D  64
#define NBLK 391  // ceil(NN/256)

typedef _Float16 half2v __attribute__((ext_vector_type(2)));

// in-register packed entry: [col:17][ex_fp16_no_sign:15]  (col < 2^17, ex in (0,1])
__device__ __forceinline__ unsigned int pack_entry(int col, float ex) {
    unsigned short hb = __half_as_ushort(__float2half(ex));
    return ((unsigned int)col << 15) | (unsigned int)(hb & 0x7FFFu);
}
__device__ __forceinline__ float unpack_ex(unsigned int pk) {
    return __half2float(__ushort_as_half((unsigned short)(pk & 0x7FFFu)));
}

__device__ __forceinline__ float dot2acc(int a, unsigned int b, float c) {
#if defined(__has_builtin) && __has_builtin(__builtin_amdgcn_fdot2)
    return __builtin_amdgcn_fdot2(__builtin_bit_cast(half2v, a),
                                  __builtin_bit_cast(half2v, b), c, false);
#else
    float2 fa = __half22float2(*(const __half2*)&a);
    float2 fb = __half22float2(*(const __half2*)&b);
    return fmaf(fa.y, fb.y, fmaf(fa.x, fb.x, c));
#endif
}

// ---------------- K_prep_count: zx[n][0:64]=z/||z||, zx[n][64:128]=x@W^T (fp16);
//                  count phase into per-virtual-XCD histogram cnt8[bid&7][r] ----------------
__global__ __launch_bounds__(256) void k_prep_count(const float* __restrict__ z,
                                                    const float* __restrict__ x,
                                                    const float* __restrict__ W,
                                                    __half* __restrict__ zx,
                                                    const int* __restrict__ ei,
                                                    int* __restrict__ cnt8,
                                                    unsigned int* __restrict__ rankr) {
    __shared__ unsigned int WtP[32 * 64];  // WtP[d2*64 + j] = half2(W[j][2*d2], W[j][2*d2+1]), 8 KB
    {
        const float2* W2 = (const float2*)W;
        for (int i = threadIdx.x; i < 2048; i += 256) {
            int j = i >> 5, d2 = i & 31;
            float2 wp = W2[j * 32 + d2];  // coalesced pair read of row j
            half2v h;
            h.x = (_Float16)wp.x;
            h.y = (_Float16)wp.y;
            WtP[d2 * 64 + j] = __builtin_bit_cast(unsigned int, h);
        }
    }
    __syncthreads();
    const int lane = threadIdx.x & 63;
    int wave = blockIdx.x * 4 + (threadIdx.x >> 6);
    int nWaves = gridDim.x * 4;
    for (int n = wave; n < NN; n += nWaves) {
        float zv = z[n * D + lane];
        float s = zv * zv;
#pragma unroll
        for (int off = 32; off; off >>= 1) s += __shfl_xor(s, off);
        float inv = 1.0f / sqrtf(fmaxf(s, 1e-18f));
        zx[(size_t)n * 128 + lane] = __float2half(zv * inv);
        // pack x row into lane-held half2 pairs: lane i holds (x[2*(i&31)], x[2*(i&31)+1])
        float xv = x[n * D + lane];
        float pa = __shfl(xv, 2 * (lane & 31));
        float pb = __shfl(xv, 2 * (lane & 31) + 1);
        half2v pkh;
        pkh.x = (_Float16)pa;
        pkh.y = (_Float16)pb;
        int pki = __builtin_bit_cast(int, pkh);
        float y = 0.0f;
#pragma unroll
        for (int d2 = 0; d2 < 32; ++d2) {
            int pv = __shfl(pki, d2);            // (x[2*d2], x[2*d2+1]) broadcast
            unsigned int wv = WtP[d2 * 64 + lane];  // conflict-free
            y = dot2acc(pv, wv, y);
        }
        zx[(size_t)n * 128 + 64 + lane] = __float2half(y);
    }
    // ---- count phase: per-virtual-XCD histogram (cnt8 pre-zeroed) ----
    const int myc = (blockIdx.x & 7) * NN;
    const unsigned int xcdbits = (unsigned int)(blockIdx.x & 7) << 12;
    int i = blockIdx.x * 256 + threadIdx.x;
    int stride = gridDim.x * 256;
    for (int e = i; e < NE; e += stride) {
        int r = __builtin_nontemporal_load(&ei[e]);
        int rk = atomicAdd(&cnt8[myc + r], 1);
        // [r:17][xcd:3][rank:12]
        __builtin_nontemporal_store(((unsigned int)r << 15) | xcdbits | (unsigned int)rk,
                                    &rankr[e]);
    }
}

// ---------------- scan: exclusive prefix sum over row totals ----------------
__global__ __launch_bounds__(256) void k_scan1(const int* __restrict__ cnt8,
                                               int* __restrict__ inc,
                                               int* __restrict__ bsum) {
    __shared__ int sh[256];
    int gid = blockIdx.x * 256 + threadIdx.x;
    int v = 0;
    if (gid < NN) {
#pragma unroll
        for (int k = 0; k < 8; ++k) v += cnt8[k * NN + gid];
    }
    sh[threadIdx.x] = v;
    __syncthreads();
    for (int off = 1; off < 256; off <<= 1) {
        int t = (threadIdx.x >= off) ? sh[threadIdx.x - off] : 0;
        __syncthreads();
        sh[threadIdx.x] += t;
        __syncthreads();
    }
    if (gid < NN) inc[gid] = sh[threadIdx.x];
    if (threadIdx.x == 255) bsum[blockIdx.x] = sh[255];
}

__global__ __launch_bounds__(512) void k_scan2(int* __restrict__ bsum) {
    __shared__ int sh[512];
    int v = (threadIdx.x < NBLK) ? bsum[threadIdx.x] : 0;
    sh[threadIdx.x] = v;
    __syncthreads();
    for (int off = 1; off < 512; off <<= 1) {
        int t = (threadIdx.x >= off) ? sh[threadIdx.x - off] : 0;
        __syncthreads();
        sh[threadIdx.x] += t;
        __syncthreads();
    }
    if (threadIdx.x < NBLK) bsum[threadIdx.x] = sh[threadIdx.x] - v;  // exclusive
}

__global__ __launch_bounds__(256) void k_scan3(const int* __restrict__ cnt8,
                                               const int* __restrict__ inc,
                                               const int* __restrict__ bsum,
                                               int* __restrict__ row_start,
                                               int* __restrict__ row_start8,
                                               int* __restrict__ tot) {
    int gid = blockIdx.x * 256 + threadIdx.x;
    if (gid >= NN) return;
    int c[8];
    int s8 = 0;
#pragma unroll
    for (int k = 0; k < 8; ++k) {
        c[k] = cnt8[k * NN + gid];
        s8 += c[k];
    }
    int ex = inc[gid] - s8 + bsum[blockIdx.x];
    row_start[gid] = ex;
    tot[gid] = s8;
    int base = ex;
#pragma unroll
    for (int k = 0; k < 8; ++k) {
        row_start8[k * NN + gid] = base;
        base += c[k];
    }
}

// ---------------- K_place: atomic-free colidx scatter via per-XCD offsets ----------------
__global__ __launch_bounds__(256) void k_place(const int* __restrict__ ei,
                                               const unsigned int* __restrict__ rankr,
                                               const int* __restrict__ row_start8,
                                               int* __restrict__ colidx) {
    int e = blockIdx.x * 256 + threadIdx.x;
    if (e >= NE) return;
    unsigned int rr = __builtin_nontemporal_load(&rankr[e]);
    int c = __builtin_nontemporal_load(&ei[NE + e]);
    int r = (int)(rr >> 15);
    int xcd = (int)((rr >> 12) & 7u);
    int rk = (int)(rr & 0xFFFu);
    __builtin_nontemporal_store(c, &colidx[row_start8[xcd * NN + r] + rk]);
}

// ---------------- K_node: fused per-node dot+exp+softmax+gather (+bias) ----------------
__global__ __launch_bounds__(256) void k_node(const __half* __restrict__ zx,
                                              const int* __restrict__ colidx,
                                              const int* __restrict__ row_start,
                                              const int* __restrict__ tot,
                                              const float* __restrict__ b,
                                              const float* __restrict__ alpha_p,
                                              const float* __restrict__ bias_p,
                                              float* __restrict__ out) {
    const int lane = threadIdx.x & 63;
    int n = (blockIdx.x * blockDim.x + threadIdx.x) >> 6;  // one wave per node
    if (n >= NN) return;
    const float alpha = *alpha_p;
    const float bias = *bias_p;
    const float Mest = fabsf(alpha) + bias;  // >= max logit since |corr| <= 1
    int rs = row_start[n];
    int c = tot[n];
    float bv = b[lane];
    const float4* zi4 = (const float4*)(zx + (size_t)n * 128);
    float4 zi[8];
#pragma unroll
    for (int k = 0; k < 8; ++k) zi[k] = zi4[k];
    float acc = 0.0f;
    float dsum = 0.0f;
    for (int base = 0; base < c; base += 64) {
        int m = min(64, c - base);
        int idx = base + lane;
        int col = (idx < c) ? colidx[rs + idx] : 0;
        // ---- phase A: in-lane dot(zn[n], zn[col]) ----
        const float4* zj4 = (const float4*)(zx + (size_t)col * 128);
        float4 zj[8];
#pragma unroll
        for (int k = 0; k < 8; ++k) zj[k] = zj4[k];
        float dot = 0.0f;
#pragma unroll
        for (int k = 0; k < 8; ++k) {
            const int* ha = (const int*)&zi[k];
            const unsigned int* hb = (const unsigned int*)&zj[k];
#pragma unroll
            for (int q = 0; q < 4; ++q) dot = dot2acc(ha[q], hb[q], dot);
        }
        float ex = (idx < c) ? __expf(alpha * dot + bias - Mest) : 0.0f;
        unsigned int pk = pack_entry(col, ex);
        float t = ex;
#pragma unroll
        for (int off = 32; off; off >>= 1) t += __shfl_xor(t, off);
        dsum += t;
        // ---- phase B: broadcast + coalesced xw gather (second half of zx row) ----
        int j = 0;
        for (; j + 8 <= m; j += 8) {
            unsigned int p0 = (unsigned int)__builtin_amdgcn_readlane((int)pk, j);
            unsigned int p1 = (unsigned int)__builtin_amdgcn_readlane((int)pk, j + 1);
            unsigned int p2 = (unsigned int)__builtin_amdgcn_readlane((int)pk, j + 2);
            unsigned int p3 = (unsigned int)__builtin_amdgcn_readlane((int)pk, j + 3);
            unsigned int p4 = (unsigned int)__builtin_amdgcn_readlane((int)pk, j + 4);
            unsigned int p5 = (unsigned int)__builtin_amdgcn_readlane((int)pk, j + 5);
            unsigned int p6 = (unsigned int)__builtin_amdgcn_readlane((int)pk, j + 6);
            unsigned int p7 = (unsigned int)__builtin_amdgcn_readlane((int)pk, j + 7);
            float x0 = __half2float(zx[(size_t)(p0 >> 15) * 128 + 64 + lane]);
            float x1 = __half2float(zx[(size_t)(p1 >> 15) * 128 + 64 + lane]);
            float x2 = __half2float(zx[(size_t)(p2 >> 15) * 128 + 64 + lane]);
            float x3 = __half2float(zx[(size_t)(p3 >> 15) * 128 + 64 + lane]);
            float x4 = __half2float(zx[(size_t)(p4 >> 15) * 128 + 64 + lane]);
            float x5 = __half2float(zx[(size_t)(p5 >> 15) * 128 + 64 + lane]);
            float x6 = __half2float(zx[(size_t)(p6 >> 15) * 128 + 64 + lane]);
            float x7 = __half2float(zx[(size_t)(p7 >> 15) * 128 + 64 + lane]);
            acc = fmaf(unpack_ex(p0), x0, acc);
            acc = fmaf(unpack_ex(p1), x1, acc);
            acc = fmaf(unpack_ex(p2), x2, acc);
            acc = fmaf(unpack_ex(p3), x3, acc);
            acc = fmaf(unpack_ex(p4), x4, acc);
            acc = fmaf(unpack_ex(p5), x5, acc);
            acc = fmaf(unpack_ex(p6), x6, acc);
            acc = fmaf(unpack_ex(p7), x7, acc);
        }
        for (; j < m; ++j) {
            unsigned int p0 = (unsigned int)__builtin_amdgcn_readlane((int)pk, j);
            float x0 = __half2float(zx[(size_t)(p0 >> 15) * 128 + 64 + lane]);
            acc = fmaf(unpack_ex(p0), x0, acc);
        }
    }
    out[n * D + lane] = acc / (dsum + 1e-9f) + bv;
}

extern "C" void kernel_launch(void* const* d_in, const int* in_sizes, int n_in,
                              void* d_out, int out_size, void* d_ws, size_t ws_size,
                              hipStream_t stream) {
    const float* x = (const float*)d_in[0];
    const int* ei = (const int*)d_in[1];  // [2, NE] int32
    const float* z = (const float*)d_in[2];
    const float* W = (const float*)d_in[3];
    const float* b = (const float*)d_in[4];
    const float* alpha = (const float*)d_in[5];
    const float* bias_edge = (const float*)d_in[6];
    float* out = (float*)d_out;  // [NN, D]

    // workspace layout (~46 MB)
    char* ws = (char*)d_ws;
    size_t off = 0;
    __half* zx = (__half*)(ws + off); off += (size_t)NN * 128 * 2;           // 25.6 MB
    int* colidx = (int*)(ws + off); off += (size_t)NE * 4;                   // 6.4 MB
    unsigned int* rankr = (unsigned int*)(ws + off); off += (size_t)NE * 4;  // 6.4 MB
    int* cnt8 = (int*)(ws + off); off += (size_t)8 * NN * 4;                 // 3.2 MB
    int* row_start8 = (int*)(ws + off); off += (size_t)8 * NN * 4;           // 3.2 MB
    int* inc = (int*)(ws + off); off += (size_t)NN * 4;
    int* row_start = (int*)(ws + off); off += (size_t)NN * 4;
    int* tot = (int*)(ws + off); off += (size_t)NN * 4;
    int* bsum = (int*)(ws + off); off += 512 * 4;

    hipMemsetAsync(cnt8, 0, (size_t)8 * NN * 4, stream);
    k_prep_count<<<4096, 256, 0, stream>>>(z, x, W, zx, ei, cnt8, rankr);
    k_scan1<<<NBLK, 256, 0, stream>>>(cnt8, inc, bsum);
    k_scan2<<<1, 512, 0, stream>>>(bsum);
    k_scan3<<<NBLK, 256, 0, stream>>>(cnt8, inc, bsum, row_start, row_start8, tot);
    k_place<<<(NE + 255) / 256, 256, 0, stream>>>(ei, rankr, row_start8, colidx);
    k_node<<<(NN * 64 + 255) / 256, 256, 0, stream>>>(zx, colidx, row_start, tot, b, alpha, bias_edge, out);
}

// Round 13
// 229.634 us; speedup vs baseline: 1.3628x; 1.0644x over previous
//
#include <hip/hip_runtime.h>
#include <hip/hip_fp16.h>
#include <math.h>

#define NN 100000
#define NE 1600000
#define D  64
#define NBLK 391  // ceil(NN/256)

typedef _Float16 half2v __attribute__((ext_vector_type(2)));

// in-register packed entry: [col:17][ex_fp16_no_sign:15]  (col < 2^17, ex in (0,1])
__device__ __forceinline__ unsigned int pack_entry(int col, float ex) {
    unsigned short hb = __half_as_ushort(__float2half(ex));
    return ((unsigned int)col << 15) | (unsigned int)(hb & 0x7FFFu);
}
__device__ __forceinline__ float unpack_ex(unsigned int pk) {
    return __half2float(__ushort_as_half((unsigned short)(pk & 0x7FFFu)));
}

__device__ __forceinline__ float dot2acc(int a, unsigned int b, float c) {
#if defined(__has_builtin) && __has_builtin(__builtin_amdgcn_fdot2)
    return __builtin_amdgcn_fdot2(__builtin_bit_cast(half2v, a),
                                  __builtin_bit_cast(half2v, b), c, false);
#else
    float2 fa = __half22float2(*(const __half2*)&a);
    float2 fb = __half22float2(*(const __half2*)&b);
    return fmaf(fa.y, fb.y, fmaf(fa.x, fb.x, c));
#endif
}

// ---------------- K_prep_count: zx[n][0:64]=z/||z||, zx[n][64:128]=x@W^T (fp16);
//                  count phase into per-virtual-XCD histogram cnt8[bid&7][r] ----------------
__global__ __launch_bounds__(256) void k_prep_count(const float* __restrict__ z,
                                                    const float* __restrict__ x,
                                                    const float* __restrict__ W,
                                                    __half* __restrict__ zx,
                                                    const int* __restrict__ ei,
                                                    int* __restrict__ cnt8,
                                                    unsigned int* __restrict__ rankr) {
    __shared__ unsigned int WtP[32 * 64];  // WtP[d2*64 + j] = half2(W[j][2*d2], W[j][2*d2+1]), 8 KB
    {
        const float2* W2 = (const float2*)W;
        for (int i = threadIdx.x; i < 2048; i += 256) {
            int j = i >> 5, d2 = i & 31;
            float2 wp = W2[j * 32 + d2];  // coalesced pair read of row j
            half2v h;
            h.x = (_Float16)wp.x;
            h.y = (_Float16)wp.y;
            WtP[d2 * 64 + j] = __builtin_bit_cast(unsigned int, h);
        }
    }
    __syncthreads();
    const int lane = threadIdx.x & 63;
    int wave = blockIdx.x * 4 + (threadIdx.x >> 6);
    int nWaves = gridDim.x * 4;
    for (int n = wave; n < NN; n += nWaves) {
        float zv = z[n * D + lane];
        float s = zv * zv;
#pragma unroll
        for (int off = 32; off; off >>= 1) s += __shfl_xor(s, off);
        float inv = 1.0f / sqrtf(fmaxf(s, 1e-18f));
        zx[(size_t)n * 128 + lane] = __float2half(zv * inv);
        // pack x row into lane-held half2 pairs: lane i holds (x[2*(i&31)], x[2*(i&31)+1])
        float xv = x[n * D + lane];
        float pa = __shfl(xv, 2 * (lane & 31));
        float pb = __shfl(xv, 2 * (lane & 31) + 1);
        half2v pkh;
        pkh.x = (_Float16)pa;
        pkh.y = (_Float16)pb;
        int pki = __builtin_bit_cast(int, pkh);
        float y = 0.0f;
#pragma unroll
        for (int d2 = 0; d2 < 32; ++d2) {
            int pv = __shfl(pki, d2);               // (x[2*d2], x[2*d2+1]) broadcast
            unsigned int wv = WtP[d2 * 64 + lane];  // conflict-free
            y = dot2acc(pv, wv, y);
        }
        zx[(size_t)n * 128 + 64 + lane] = __float2half(y);
    }
    // ---- count phase: per-virtual-XCD histogram (cnt8 pre-zeroed) ----
    const int myc = (blockIdx.x & 7) * NN;
    const unsigned int xcdbits = (unsigned int)(blockIdx.x & 7) << 12;
    int i = blockIdx.x * 256 + threadIdx.x;
    int stride = gridDim.x * 256;
    for (int e = i; e < NE; e += stride) {
        int r = __builtin_nontemporal_load(&ei[e]);
        int rk = atomicAdd(&cnt8[myc + r], 1);
        // [r:17][xcd:3][rank:12]
        __builtin_nontemporal_store(((unsigned int)r << 15) | xcdbits | (unsigned int)rk,
                                    &rankr[e]);
    }
}

// ---------------- scan: exclusive prefix sum over row totals ----------------
__global__ __launch_bounds__(256) void k_scan1(const int* __restrict__ cnt8,
                                               int* __restrict__ inc,
                                               int* __restrict__ bsum) {
    __shared__ int sh[256];
    int gid = blockIdx.x * 256 + threadIdx.x;
    int v = 0;
    if (gid < NN) {
#pragma unroll
        for (int k = 0; k < 8; ++k) v += cnt8[k * NN + gid];
    }
    sh[threadIdx.x] = v;
    __syncthreads();
    for (int off = 1; off < 256; off <<= 1) {
        int t = (threadIdx.x >= off) ? sh[threadIdx.x - off] : 0;
        __syncthreads();
        sh[threadIdx.x] += t;
        __syncthreads();
    }
    if (gid < NN) inc[gid] = sh[threadIdx.x];
    if (threadIdx.x == 255) bsum[blockIdx.x] = sh[255];
}

__global__ __launch_bounds__(512) void k_scan2(int* __restrict__ bsum) {
    __shared__ int sh[512];
    int v = (threadIdx.x < NBLK) ? bsum[threadIdx.x] : 0;
    sh[threadIdx.x] = v;
    __syncthreads();
    for (int off = 1; off < 512; off <<= 1) {
        int t = (threadIdx.x >= off) ? sh[threadIdx.x - off] : 0;
        __syncthreads();
        sh[threadIdx.x] += t;
        __syncthreads();
    }
    if (threadIdx.x < NBLK) bsum[threadIdx.x] = sh[threadIdx.x] - v;  // exclusive
}

__global__ __launch_bounds__(256) void k_scan3(const int* __restrict__ cnt8,
                                               const int* __restrict__ inc,
                                               const int* __restrict__ bsum,
                                               int* __restrict__ row_start,
                                               int* __restrict__ row_start8,
                                               int* __restrict__ tot) {
    int gid = blockIdx.x * 256 + threadIdx.x;
    if (gid >= NN) return;
    int c[8];
    int s8 = 0;
#pragma unroll
    for (int k = 0; k < 8; ++k) {
        c[k] = cnt8[k * NN + gid];
        s8 += c[k];
    }
    int ex = inc[gid] - s8 + bsum[blockIdx.x];
    row_start[gid] = ex;
    tot[gid] = s8;
    int base = ex;
#pragma unroll
    for (int k = 0; k < 8; ++k) {
        row_start8[k * NN + gid] = base;
        base += c[k];
    }
}

// ---------------- K_place: atomic-free colidx scatter via per-XCD offsets ----------------
__global__ __launch_bounds__(256) void k_place(const int* __restrict__ ei,
                                               const unsigned int* __restrict__ rankr,
                                               const int* __restrict__ row_start8,
                                               int* __restrict__ colidx) {
    int e = blockIdx.x * 256 + threadIdx.x;
    if (e >= NE) return;
    unsigned int rr = __builtin_nontemporal_load(&rankr[e]);
    int c = __builtin_nontemporal_load(&ei[NE + e]);
    int r = (int)(rr >> 15);
    int xcd = (int)((rr >> 12) & 7u);
    int rk = (int)(rr & 0xFFFu);
    __builtin_nontemporal_store(c, &colidx[row_start8[xcd * NN + r] + rk]);
}

// ---------------- K_node: 4 nodes per wave (16 lanes each); fused dot+exp+softmax+gather ----------------
__global__ __launch_bounds__(256) void k_node(const __half* __restrict__ zx,
                                              const int* __restrict__ colidx,
                                              const int* __restrict__ row_start,
                                              const int* __restrict__ tot,
                                              const float* __restrict__ b,
                                              const float* __restrict__ alpha_p,
                                              const float* __restrict__ bias_p,
                                              float* __restrict__ out) {
    const int lane = threadIdx.x & 63;
    const int sub = lane & 15;  // edge slot within my node's group
    int w = (blockIdx.x * blockDim.x + threadIdx.x) >> 6;
    int nb = w * 4;  // 4 nodes per wave; grid sized exactly: nb+3 <= NN-1
    int n = nb + (lane >> 4);
    const float alpha = *alpha_p;
    const float bias = *bias_p;
    const float Mest = fabsf(alpha) + bias;  // >= max logit since |corr| <= 1
    int rs = row_start[n];
    int c = tot[n];
    float bv = b[lane];
    // zi: my group's node row (16 lanes share a row -> requests merge; 4 rows per wave)
    const float4* zi4 = (const float4*)(zx + (size_t)n * 128);
    float4 zi[8];
#pragma unroll
    for (int k = 0; k < 8; ++k) zi[k] = zi4[k];
    // max chunk count across the 4 groups
    int cmax = c;
    cmax = max(cmax, __shfl_xor(cmax, 16));
    cmax = max(cmax, __shfl_xor(cmax, 32));
    // accumulators: lane holds dim=lane for each of the 4 nodes, 2 chains each
    float a0A = 0.0f, a0B = 0.0f, a1A = 0.0f, a1B = 0.0f;
    float a2A = 0.0f, a2B = 0.0f, a3A = 0.0f, a3B = 0.0f;
    float dsum = 0.0f;  // my group's denom (uniform within group after butterflies)
    for (int base = 0; base < cmax; base += 16) {
        int idx = base + sub;
        bool valid = idx < c;
        int col = valid ? colidx[rs + idx] : 0;
        // ---- phase A: in-lane dot(zn[n], zn[col]), 4 independent fdot2 chains ----
        const float4* zj4 = (const float4*)(zx + (size_t)col * 128);
        float4 zj[8];
#pragma unroll
        for (int k = 0; k < 8; ++k) zj[k] = zj4[k];
        float d0 = 0.0f, d1 = 0.0f, d2 = 0.0f, d3 = 0.0f;
#pragma unroll
        for (int k = 0; k < 8; ++k) {
            const int* ha = (const int*)&zi[k];
            const unsigned int* hb = (const unsigned int*)&zj[k];
            d0 = dot2acc(ha[0], hb[0], d0);
            d1 = dot2acc(ha[1], hb[1], d1);
            d2 = dot2acc(ha[2], hb[2], d2);
            d3 = dot2acc(ha[3], hb[3], d3);
        }
        float dot = (d0 + d1) + (d2 + d3);
        float ex = valid ? __expf(alpha * dot + bias - Mest) : 0.0f;
        unsigned int pk = pack_entry(col, ex);
        // group-local denom butterfly (4 steps over 16 lanes)
        float t = ex;
        t += __shfl_xor(t, 1);
        t += __shfl_xor(t, 2);
        t += __shfl_xor(t, 4);
        t += __shfl_xor(t, 8);
        dsum += t;
        // ---- phase B: per group, broadcast + coalesced xw gather ----
#define PHASE_B(GG, ACCA, ACCB)                                                                    \
        {                                                                                          \
            int cg = __shfl(c, GG * 16);                                                           \
            int mg = cg - base;                                                                    \
            mg = mg > 16 ? 16 : mg;                                                               \
            int j = 0;                                                                             \
            for (; j + 4 <= mg; j += 4) {                                                          \
                unsigned int q0 = (unsigned int)__builtin_amdgcn_readlane((int)pk, GG * 16 + j);   \
                unsigned int q1 = (unsigned int)__builtin_amdgcn_readlane((int)pk, GG * 16 + j + 1); \
                unsigned int q2 = (unsigned int)__builtin_amdgcn_readlane((int)pk, GG * 16 + j + 2); \
                unsigned int q3 = (unsigned int)__builtin_amdgcn_readlane((int)pk, GG * 16 + j + 3); \
                float x0 = __half2float(zx[(size_t)(q0 >> 15) * 128 + 64 + lane]);                 \
                float x1 = __half2float(zx[(size_t)(q1 >> 15) * 128 + 64 + lane]);                 \
                float x2 = __half2float(zx[(size_t)(q2 >> 15) * 128 + 64 + lane]);                 \
                float x3 = __half2float(zx[(size_t)(q3 >> 15) * 128 + 64 + lane]);                 \
                ACCA = fmaf(unpack_ex(q0), x0, ACCA);                                              \
                ACCB = fmaf(unpack_ex(q1), x1, ACCB);                                              \
                ACCA = fmaf(unpack_ex(q2), x2, ACCA);                                              \
                ACCB = fmaf(unpack_ex(q3), x3, ACCB);                                              \
            }                                                                                      \
            for (; j < mg; ++j) {                                                                  \
                unsigned int q0 = (unsigned int)__builtin_amdgcn_readlane((int)pk, GG * 16 + j);   \
                float x0 = __half2float(zx[(size_t)(q0 >> 15) * 128 + 64 + lane]);                 \
                ACCA = fmaf(unpack_ex(q0), x0, ACCA);                                              \
            }                                                                                      \
        }
        PHASE_B(0, a0A, a0B)
        PHASE_B(1, a1A, a1B)
        PHASE_B(2, a2A, a2B)
        PHASE_B(3, a3A, a3B)
#undef PHASE_B
    }
    float dg0 = __shfl(dsum, 0);
    float dg1 = __shfl(dsum, 16);
    float dg2 = __shfl(dsum, 32);
    float dg3 = __shfl(dsum, 48);
    out[(size_t)(nb + 0) * D + lane] = (a0A + a0B) / (dg0 + 1e-9f) + bv;
    out[(size_t)(nb + 1) * D + lane] = (a1A + a1B) / (dg1 + 1e-9f) + bv;
    out[(size_t)(nb + 2) * D + lane] = (a2A + a2B) / (dg2 + 1e-9f) + bv;
    out[(size_t)(nb + 3) * D + lane] = (a3A + a3B) / (dg3 + 1e-9f) + bv;
}

extern "C" void kernel_launch(void* const* d_in, const int* in_sizes, int n_in,
                              void* d_out, int out_size, void* d_ws, size_t ws_size,
                              hipStream_t stream) {
    const float* x = (const float*)d_in[0];
    const int* ei = (const int*)d_in[1];  // [2, NE] int32
    const float* z = (const float*)d_in[2];
    const float* W = (const float*)d_in[3];
    const float* b = (const float*)d_in[4];
    const float* alpha = (const float*)d_in[5];
    const float* bias_edge = (const float*)d_in[6];
    float* out = (float*)d_out;  // [NN, D]

    // workspace layout (~46 MB)
    char* ws = (char*)d_ws;
    size_t off = 0;
    __half* zx = (__half*)(ws + off); off += (size_t)NN * 128 * 2;           // 25.6 MB
    int* colidx = (int*)(ws + off); off += (size_t)NE * 4;                   // 6.4 MB
    unsigned int* rankr = (unsigned int*)(ws + off); off += (size_t)NE * 4;  // 6.4 MB
    int* cnt8 = (int*)(ws + off); off += (size_t)8 * NN * 4;                 // 3.2 MB
    int* row_start8 = (int*)(ws + off); off += (size_t)8 * NN * 4;           // 3.2 MB
    int* inc = (int*)(ws + off); off += (size_t)NN * 4;
    int* row_start = (int*)(ws + off); off += (size_t)NN * 4;
    int* tot = (int*)(ws + off); off += (size_t)NN * 4;
    int* bsum = (int*)(ws + off); off += 512 * 4;

    hipMemsetAsync(cnt8, 0, (size_t)8 * NN * 4, stream);
    k_prep_count<<<4096, 256, 0, stream>>>(z, x, W, zx, ei, cnt8, rankr);
    k_scan1<<<NBLK, 256, 0, stream>>>(cnt8, inc, bsum);
    k_scan2<<<1, 512, 0, stream>>>(bsum);
    k_scan3<<<NBLK, 256, 0, stream>>>(cnt8, inc, bsum, row_start, row_start8, tot);
    k_place<<<(NE + 255) / 256, 256, 0, stream>>>(ei, rankr, row_start8, colidx);
    // 4 nodes per wave, 16 nodes per 256-thread block -> exactly NN/16 = 6250 blocks
    k_node<<<NN / 16, 256, 0, stream>>>(zx, colidx, row_start, tot, b, alpha, bias_edge, out);
}